// Round 11
// baseline (186.359 us; speedup 1.0000x reference)
//
#include <hip/hip_runtime.h>
#include <hip/hip_fp16.h>

#define DIM 128
#define HEADS 4
#define ODIM 32
#define LRELU 0.2f
#define PT 4096
#define CAP 9216

typedef unsigned int u32;
typedef unsigned short u16;
typedef unsigned char u8;

typedef __attribute__((ext_vector_type(8))) short bf16x8;
typedef __attribute__((ext_vector_type(4))) float f32x4;

__device__ __forceinline__ u16 f2bf(float f) {
    union { u32 u; float f; } x; x.f = f;
    u32 u = x.u;
    u32 r = u + 0x7FFFu + ((u >> 16) & 1u);
    return (u16)(r >> 16);
}
__device__ __forceinline__ u32 pack_h2(float x, float y) {
    union { __half2 h; u32 u; } c;
    c.h = __floats2half2_rn(x, y);
    return c.u;
}
__device__ __forceinline__ float2 up2(u32 b) {
    union { u32 u; __half2 h; } c; c.u = b;
    return __half22float2(c.h);
}

// ---------------------------------------------------------------------------
// shfl-based exclusive scan over 256 threads
// ---------------------------------------------------------------------------
__device__ __forceinline__ int scan256_excl(int v, int t, int* wsum) {
    int lane = t & 63, w = t >> 6;
    int inc = v;
    #pragma unroll
    for (int ofs = 1; ofs < 64; ofs <<= 1) {
        int x = __shfl_up(inc, ofs);
        if (lane >= ofs) inc += x;
    }
    __syncthreads();
    if (lane == 63) wsum[w] = inc;
    __syncthreads();
    int add = 0;
    #pragma unroll
    for (int j = 0; j < 4; ++j) add += (j < w) ? wsum[j] : 0;
    return inc - v + add;
}

// ---------------------------------------------------------------------------
// Wt-transpose body: Wt[n][k] = bf16(W[k][n]), 8 blocks (k-sliced).
// Runs inside K2 (partition kernel); proj (K3) consumes Wt after K2 completes.
// ---------------------------------------------------------------------------
__device__ __forceinline__ void wtprep_body(
    char* smem, int b, const float* __restrict__ W, u16* __restrict__ Wt)
{
    u16* s = (u16*)smem;                       // 128*17 u16 = 4.3 KB
    const int t = threadIdx.x;
    #pragma unroll
    for (int i = 0; i < 8; ++i) {
        int idx = i * 256 + t;                 // 0..2047
        int kk = idx >> 7;                     // 0..15
        int nn = idx & 127;
        s[nn * 17 + kk] = f2bf(W[(b * 16 + kk) * 128 + nn]);  // coalesced read
    }
    __syncthreads();
    #pragma unroll
    for (int i = 0; i < 8; ++i) {
        int idx = i * 256 + t;
        int nn = idx >> 4;                     // 0..127
        int kk = idx & 15;
        Wt[nn * 128 + b * 16 + kk] = s[nn * 17 + kk];         // 32B bursts
    }
}

// ---------------------------------------------------------------------------
// partition body: LDS-staged, 4-way privatized hists/cursors.
// bcur is ZERO-initialized (memset); global base = t*CAP + atomic offset.
// ---------------------------------------------------------------------------
__device__ __forceinline__ void partition_body(
    char* smem, int bid, const int* __restrict__ ei, int* __restrict__ bcur,
    u32* __restrict__ part, int E, int n)
{
    u32* stage = (u32*)smem;
    u8*  sbkt  = (u8*)(smem + 16384);
    int (*lcnt4)[256] = (int (*)[256])(smem + 20480);
    int (*lcur4)[256] = (int (*)[256])(smem + 24576);
    int* loff  = (int*)(smem + 28672);
    int* ltot  = (int*)(smem + 29696);
    int* gbase = (int*)(smem + 30720);
    int* wsum  = (int*)(smem + 31744);
    const int t = threadIdx.x;
    const int wv = t >> 6;
    const int base = bid * PT;
    lcnt4[0][t] = 0; lcnt4[1][t] = 0; lcnt4[2][t] = 0; lcnt4[3][t] = 0;
    __syncthreads();

    // batched edge loads (independent -> high MLP), then keys, then atomics
    int srcv[16], tgtv[16];
    #pragma unroll
    for (int i = 0; i < 16; ++i) {
        int e = base + i * 256 + t;
        srcv[i] = (e < E) ? ei[e] : -1;
    }
    #pragma unroll
    for (int i = 0; i < 16; ++i) {
        int e = base + i * 256 + t;
        tgtv[i] = (e < E) ? ei[E + e] : 0;
    }
    u32 key[16];
    int bkt[16];
    #pragma unroll
    for (int i = 0; i < 16; ++i) {
        bkt[i] = -1;
        key[i] = 0;
        if (srcv[i] >= 0) {
            int src = min(srcv[i], n - 1);
            int tgt = max(0, min(tgtv[i], n - 1));
            bkt[i] = src >> 8;
            key[i] = ((u32)(src & 255) << 17) | (u32)tgt;
        }
    }
    #pragma unroll
    for (int i = 0; i < 16; ++i)
        if (bkt[i] >= 0) atomicAdd(&lcnt4[wv][bkt[i]], 1);
    __syncthreads();
    int c0 = lcnt4[0][t], c1 = lcnt4[1][t], c2 = lcnt4[2][t], c3 = lcnt4[3][t];
    int total = c0 + c1 + c2 + c3;
    int ex = scan256_excl(total, t, wsum);
    loff[t] = ex;
    ltot[t] = total;
    lcur4[0][t] = ex;
    lcur4[1][t] = ex + c0;
    lcur4[2][t] = ex + c0 + c1;
    lcur4[3][t] = ex + c0 + c1 + c2;
    int gb = (total > 0) ? atomicAdd(&bcur[t], total) : 0;
    gbase[t] = t * CAP + gb;
    __syncthreads();
    #pragma unroll
    for (int i = 0; i < 16; ++i) {
        if (bkt[i] >= 0) {
            int p = atomicAdd(&lcur4[wv][bkt[i]], 1);
            stage[p] = key[i];
            sbkt[p] = (u8)bkt[i];
        }
    }
    __syncthreads();
    int tot = loff[255] + ltot[255];
    for (int i = t; i < tot; i += 256) {
        int b = sbkt[i];
        int dst = gbase[b] + (i - loff[b]);
        if (dst < (b + 1) * CAP) part[dst] = stage[i];   // overflow guard
    }
}

// ---------------------------------------------------------------------------
// K2: Wt-transpose blocks [0,8), partition blocks [8, 8+PB).
// ---------------------------------------------------------------------------
__global__ __launch_bounds__(256) void fused_pw_kernel(
    const float* __restrict__ W, u16* __restrict__ Wt,
    const int* __restrict__ ei, int* __restrict__ bcur, u32* __restrict__ part,
    int E, int n)
{
    __shared__ alignas(16) char smem[31760];   // max(31760 partition, 4.3K wtprep)
    const int bid = (int)blockIdx.x;
    if (bid < 8)
        wtprep_body(smem, bid, W, Wt);
    else
        partition_body(smem, bid - 8, ei, bcur, part, E, n);
}

// ---------------------------------------------------------------------------
// csrfill body (no-skey, 4.2 KB LDS): per-bucket counting sort, 2 blocks per
// bucket (node-half split), 4x-unrolled global loads. bcur[t] = bucket count.
// ---------------------------------------------------------------------------
__device__ __forceinline__ void csrfill_body(
    char* smem, int blk, const u32* __restrict__ part,
    const int* __restrict__ bcur, int* __restrict__ off,
    int* __restrict__ csr_tgt, int n, int ntiles)
{
    int (*lc4)[128]   = (int (*)[128])(smem);            // 2 KB
    int (*lcur4)[128] = (int (*)[128])(smem + 2048);     // 2 KB
    int* wsum = (int*)(smem + 4096);
    int* sBC  = (int*)(smem + 4112);                     // [0]=base [1]=cnt
    const int t = threadIdx.x;
    const int b = blk >> 1, half = blk & 1;
    const int wv = t >> 6;
    // derive bucket base/cnt from counts
    int myc = (t < ntiles) ? bcur[t] : 0;
    myc = max(0, min(myc, CAP));
    int ex = scan256_excl(myc, t, wsum);
    if (t == b) { sBC[0] = ex; sBC[1] = myc; }
    if (t < 128) { lc4[0][t] = 0; lc4[1][t] = 0; lc4[2][t] = 0; lc4[3][t] = 0; }
    __syncthreads();
    const int pbase = b * CAP;
    const int base = sBC[0], cnt = sBC[1];
    for (int i = t; i < cnt; i += 1024) {
        u32 k[4];
        #pragma unroll
        for (int u = 0; u < 4; ++u) {
            int idx = i + u * 256;
            k[u] = (idx < cnt) ? part[pbase + idx] : 0xFFFFFFFFu;
        }
        #pragma unroll
        for (int u = 0; u < 4; ++u) {
            int n8 = (int)(k[u] >> 17);
            if ((n8 >> 7) == half) atomicAdd(&lc4[wv][n8 & 127], 1);
        }
    }
    __syncthreads();
    int c0 = 0, c1 = 0, c2 = 0, c3 = 0, total = 0;
    if (t < 128) {
        c0 = lc4[0][t]; c1 = lc4[1][t]; c2 = lc4[2][t]; c3 = lc4[3][t];
        total = c0 + c1 + c2 + c3;
    }
    int ex2 = scan256_excl(total, t, wsum);
    int halfTot = wsum[0] + wsum[1];           // threads >=128 contributed 0
    int myBase = base + (half ? (cnt - halfTot) : 0);
    if (t < 128) {
        lcur4[0][t] = ex2;
        lcur4[1][t] = ex2 + c0;
        lcur4[2][t] = ex2 + c0 + c1;
        lcur4[3][t] = ex2 + c0 + c1 + c2;
        int node = b * 256 + half * 128 + t;
        if (node < n) off[node] = myBase + ex2;
    }
    if (b == ntiles - 1 && half == 0 && t == 0) off[n] = base + cnt;
    __syncthreads();
    for (int i = t; i < cnt; i += 1024) {
        u32 k[4];
        #pragma unroll
        for (int u = 0; u < 4; ++u) {
            int idx = i + u * 256;
            k[u] = (idx < cnt) ? part[pbase + idx] : 0xFFFFFFFFu;
        }
        #pragma unroll
        for (int u = 0; u < 4; ++u) {
            int n8 = (int)(k[u] >> 17);
            if ((n8 >> 7) == half) {
                int p = atomicAdd(&lcur4[wv][n8 & 127], 1);
                csr_tgt[myBase + p] = (int)(k[u] & 0x1FFFFu);
            }
        }
    }
}

// ---------------------------------------------------------------------------
// proj body: MFMA proj + fused scores. Hb packed f16x2.
// ---------------------------------------------------------------------------
__device__ __forceinline__ void proj_body(
    char* smem, int bid, const float* __restrict__ X, const u16* __restrict__ Wt,
    const float* __restrict__ AL, const float* __restrict__ AR,
    u32* __restrict__ Hb, float* __restrict__ Hs, float* __restrict__ Ht, int n)
{
    float* sH  = (float*)smem;
    float* sAL = (float*)(smem + 33792);
    float* sAR = (float*)(smem + 34304);
    const int t = threadIdx.x;
    if (t < DIM) { sAL[t] = AL[t]; sAR[t] = AR[t]; }
    const int row0 = bid * 64;
    const int w = t >> 6, lane = t & 63;
    const int quad = lane >> 4, nIdx = lane & 15;
    const int m = row0 + w * 16 + nIdx;

    f32x4 acc[8];
    #pragma unroll
    for (int c = 0; c < 8; ++c) acc[c] = (f32x4){0.f, 0.f, 0.f, 0.f};

    #pragma unroll
    for (int kq = 0; kq < 4; ++kq) {
        union { bf16x8 v; u16 e[8]; } a;
        if (m < n) {
            const float* xp = &X[(size_t)m * DIM + kq * 32 + quad * 8];
            float4 x0 = *(const float4*)xp;
            float4 x1 = *(const float4*)(xp + 4);
            a.e[0] = f2bf(x0.x); a.e[1] = f2bf(x0.y);
            a.e[2] = f2bf(x0.z); a.e[3] = f2bf(x0.w);
            a.e[4] = f2bf(x1.x); a.e[5] = f2bf(x1.y);
            a.e[6] = f2bf(x1.z); a.e[7] = f2bf(x1.w);
        } else {
            #pragma unroll
            for (int j = 0; j < 8; ++j) a.e[j] = 0;
        }
        #pragma unroll
        for (int c = 0; c < 8; ++c) {
            bf16x8 b = *(const bf16x8*)&Wt[(c * 16 + nIdx) * DIM + kq * 32 + quad * 8];
            acc[c] = __builtin_amdgcn_mfma_f32_16x16x32_bf16(a.v, b, acc[c], 0, 0, 0);
        }
    }
    #pragma unroll
    for (int c = 0; c < 8; ++c)
        #pragma unroll
        for (int r = 0; r < 4; ++r)
            sH[(w * 16 + quad * 4 + r) * 132 + c * 16 + nIdx] = acc[c][r];
    __syncthreads();

    #pragma unroll
    for (int i = 0; i < 16; ++i) {
        int idx = i * 256 + t;
        int r = idx >> 6, d2 = idx & 63;
        int gr = row0 + r;
        if (gr < n) {
            float2 hv = *(const float2*)&sH[r * 132 + 2 * d2];
            Hb[(size_t)gr * 64 + d2] = pack_h2(hv.x, hv.y);
        }
    }
    {
        int r = t >> 2, h = t & 3;
        float s = 0.f, s2 = 0.f;
        #pragma unroll
        for (int q = 0; q < ODIM; q += 4) {
            float4 hv = *(const float4*)&sH[r * 132 + h * ODIM + q];
            s  += hv.x*sAL[h*ODIM+q] + hv.y*sAL[h*ODIM+q+1] + hv.z*sAL[h*ODIM+q+2] + hv.w*sAL[h*ODIM+q+3];
            s2 += hv.x*sAR[h*ODIM+q] + hv.y*sAR[h*ODIM+q+1] + hv.z*sAR[h*ODIM+q+2] + hv.w*sAR[h*ODIM+q+3];
        }
        int gr = row0 + r;
        if (gr < n) { Hs[gr * HEADS + h] = s; Ht[gr * HEADS + h] = s2; }
    }
}

// ---------------------------------------------------------------------------
// K3: csrfill blocks [0,CB) (depends on K2 partition), proj blocks
// [CB, CB+JB) (depends on K2 Wt) -- independent of each other, overlap freely.
// ---------------------------------------------------------------------------
__global__ __launch_bounds__(256) void fused_cj_kernel(
    const float* __restrict__ X, const u16* __restrict__ Wt,
    const float* __restrict__ AL, const float* __restrict__ AR,
    u32* __restrict__ Hb, float* __restrict__ Hs, float* __restrict__ Ht,
    const u32* __restrict__ part, const int* __restrict__ bcur,
    int* __restrict__ off, int* __restrict__ csr_tgt,
    int n, int ntiles, int csrBlocks)
{
    __shared__ alignas(16) char smem[34816];   // max(4.2K csrfill, 34816 proj)
    const int bid = (int)blockIdx.x;
    if (bid < csrBlocks)
        csrfill_body(smem, bid, part, bcur, off, csr_tgt, n, ntiles);
    else
        proj_body(smem, bid - csrBlocks, X, Wt, AL, AR, Hb, Hs, Ht, n);
}

// ---------------------------------------------------------------------------
// 4) CSR-gather aggregation (r9-exact): one node per wave, 32-wide batches,
//    depth-2 tl pipeline, SGPR-scalarized gathers, f16x2 Hb rows.
// ---------------------------------------------------------------------------
__global__ __launch_bounds__(256) void agg_kernel(
    const u32* __restrict__ Hb, const float* __restrict__ Hs,
    const float* __restrict__ Ht, const int* __restrict__ off,
    const int* __restrict__ csr_tgt, float2* __restrict__ out, int n, int E)
{
    int node = (blockIdx.x * 256 + threadIdx.x) >> 6;
    int L = threadIdx.x & 63;
    if (node >= n) return;
    int lo = off[node], hi = off[node + 1];
    lo = max(0, min(lo, E));
    hi = max(lo, min(hi, E));
    if (hi <= lo) {                            // isolated node: ELU(0)=0
        out[(size_t)node * 64 + L] = {0.f, 0.f};
        return;
    }
    const int h = L >> 4;                      // accumulation head
    const int jSel = L >> 2;                   // duty edge 0..15 (and +16)
    const int hSel = L & 3;                    // duty head
    float4 hs4 = *(const float4*)&Hs[node * HEADS];
    float hsD = hSel == 0 ? hs4.x : hSel == 1 ? hs4.y : hSel == 2 ? hs4.z : hs4.w;
    float ax = 0.f, ay = 0.f, Sd = 0.f;

    int tl = csr_tgt[min(lo + (L & 31), hi - 1)];   // batch-0 tl
    for (int i = lo; i < hi; i += 32) {
        // prefetch next batch's tl (independent of this batch's compute)
        int tln = 0;
        if (i + 32 < hi) tln = csr_tgt[min(i + 32 + (L & 31), hi - 1)];
        int tA = __shfl(tl, jSel);
        int tB = __shfl(tl, jSel + 16);
        float eA = hsD + Ht[tA * HEADS + hSel];
        float eB = hsD + Ht[tB * HEADS + hSel];
        float wA = (i + jSel < hi)
                       ? __expf(fminf(eA > 0.f ? eA : LRELU * eA, 30.f)) : 0.f;
        float wB = (i + jSel + 16 < hi)
                       ? __expf(fminf(eB > 0.f ? eB : LRELU * eB, 30.f)) : 0.f;
        Sd += wA + wB;
        // scalarized gathers: tgt -> SGPR via readlane, saddr-form loads
        u32 bb[32];
        #pragma unroll
        for (int j = 0; j < 32; ++j) {
            int sj = __builtin_amdgcn_readlane(tl, j);
            bb[j] = Hb[((size_t)(u32)sj << 6) + L];
        }
        #pragma unroll
        for (int j = 0; j < 16; ++j) {
            float wj = __shfl(wA, (j << 2) | h);
            float2 f = up2(bb[j]);
            ax += wj * f.x;
            ay += wj * f.y;
        }
        #pragma unroll
        for (int j = 0; j < 16; ++j) {
            float wj = __shfl(wB, (j << 2) | h);
            float2 f = up2(bb[j + 16]);
            ax += wj * f.x;
            ay += wj * f.y;
        }
        tl = tln;
    }
    float S = 0.f;
    #pragma unroll
    for (int j = 0; j < 16; ++j) S += __shfl(Sd, (j << 2) | h);
    float inv = 1.f / (S + 1e-8f);
    float ox = ax * inv, oy = ay * inv;
    ox = ox > 0.f ? ox : (__expf(ox) - 1.f);
    oy = oy > 0.f ? oy : (__expf(oy) - 1.f);
    out[(size_t)node * 64 + L] = {ox, oy};
}

// ---------------------------------------------------------------------------
extern "C" void kernel_launch(void* const* d_in, const int* in_sizes, int n_in,
                              void* d_out, int out_size, void* d_ws, size_t ws_size,
                              hipStream_t stream) {
    const float* X  = (const float*)d_in[0];   // fp32
    const int*   EI = (const int*)d_in[1];     // int32[2E] block layout
    const float* W  = (const float*)d_in[2];   // fp32 row-major
    const float* AL = (const float*)d_in[3];
    const float* AR = (const float*)d_in[4];
    const int n = in_sizes[0] / DIM;      // 50000
    const int E = in_sizes[1] / 2;        // 1600000
    const int ntiles = (n + 255) / 256;   // 196 buckets

    char* ws = (char*)d_ws;
    size_t o = 0;
    auto alloc = [&](size_t bytes) -> void* {
        o = (o + 255) & ~(size_t)255;
        void* p = ws + o;
        o += bytes;
        return p;
    };
    int*   bcur    = (int*)alloc(256 * 4);
    u16*   Wt      = (u16*)alloc((size_t)DIM * DIM * 2);      // 32 KB
    int*   off     = (int*)alloc((size_t)(n + 1) * 4);
    float* Hs      = (float*)alloc((size_t)n * HEADS * 4);
    float* Ht      = (float*)alloc((size_t)n * HEADS * 4);
    int*   csr_tgt = (int*)alloc((size_t)E * 4);
    u32*   part    = (u32*)alloc((size_t)ntiles * CAP * 4);   // 7.2 MB
    u32*   Hb      = (u32*)alloc((size_t)n * 64 * 4);

    const int PB = (E + PT - 1) / PT;     // 391 partition blocks
    const int JB = (n + 63) / 64;         // 782 proj blocks
    const int CB = ntiles * 2;            // 392 csrfill blocks

    hipMemsetAsync(bcur, 0, 256 * 4, stream);   // zero bucket counters
    fused_pw_kernel<<<8 + PB, 256, 0, stream>>>(W, Wt, EI, bcur, part, E, n);
    fused_cj_kernel<<<CB + JB, 256, 0, stream>>>(
        X, Wt, AL, AR, Hb, Hs, Ht, part, bcur, off, csr_tgt, n, ntiles, CB);
    agg_kernel<<<(n + 3) / 4, 256, 0, stream>>>(
        Hb, Hs, Ht, off, csr_tgt, (float2*)d_out, n, E);
}